// Round 18
// baseline (283.786 us; speedup 1.0000x reference)
//
#include <hip/hip_runtime.h>
#include <math.h>

#define B_SZ 4
#define SEQ 2048
#define DM 256
#define DI 512
#define DS 16
#define DTR 16
#define NH 4
#define HD 64
#define T_TOK (B_SZ*SEQ)   // 8192
#define NCH 64             // scan time-chunks
#define CL (SEQ/NCH)       // 32
#define NSP 4              // attn KV splits
#define QSCALE 0.18033688f // 0.125 * log2(e)

typedef short bf16x8 __attribute__((ext_vector_type(8)));
typedef float f32x4  __attribute__((ext_vector_type(4)));
typedef float f32x16 __attribute__((ext_vector_type(16)));
typedef unsigned short u16;

__device__ __forceinline__ float sigmoidf_(float x){ return 1.f/(1.f+__expf(-x)); }
__device__ __forceinline__ u16 f2bf(float x){
  unsigned int u = __float_as_uint(x);
  u += 0x7fffu + ((u>>16)&1u);
  return (u16)(u>>16);
}
__device__ __forceinline__ float bf2f(u16 u){ return __uint_as_float(((unsigned)u)<<16); }
__device__ __forceinline__ unsigned cvt_pk_bf16(float lo, float hi){
  unsigned r;
  asm("v_cvt_pk_bf16_f32 %0, %1, %2" : "=v"(r) : "v"(lo), "v"(hi));
  return r;
}
__device__ __forceinline__ void permswap(unsigned &a, unsigned &b){
  asm volatile("v_permlane32_swap_b32 %0, %1" : "+v"(a), "+v"(b));
}
__device__ __forceinline__ float xor32f(float v){
  unsigned a = __float_as_uint(v), b = a;
  permswap(a, b);
  return __uint_as_float(a);
}

// ---------------- all weight transposes in one kernel: dst[n][k] = bf16(src[k][n]) ----------------
struct TcvtArgs {
  const float* src[6];
  u16* dst[6];
  int K[6];
  int Nvalid[6];
  int Npad[6];
};
__global__ __launch_bounds__(256) void tcvt_all(TcvtArgs a) {
  int wi = blockIdx.z;
  int K = a.K[wi], Nv = a.Nvalid[wi], Np = a.Npad[wi];
  int k0 = blockIdx.x*64, n0 = blockIdx.y*64;
  if (k0 >= K || n0 >= Np) return;
  __shared__ u16 tile[64][65];
  const float* src = a.src[wi];
  u16* dst = a.dst[wi];
  int tn = threadIdx.x & 63, tq = threadIdx.x >> 6;
#pragma unroll
  for (int j=0;j<16;++j){
    int kk = j*4 + tq;
    int n = n0 + tn;
    tile[tn][kk] = (n < Nv) ? f2bf(src[(size_t)(k0+kk)*Nv + n]) : (u16)0;
  }
  __syncthreads();
#pragma unroll
  for (int j=0;j<16;++j){
    int nn = j*4 + tq;
    dst[(size_t)(n0+nn)*K + k0 + tn] = tile[nn][tn];
  }
}

// ---------------- LayerNorm: one wave per token -> bf16 ----------------
__global__ __launch_bounds__(256) void ln_kernel(const float* __restrict__ x,
    const float* __restrict__ g, const float* __restrict__ b,
    u16* __restrict__ xn_bf) {
  int wid = threadIdx.x >> 6;
  int lane = threadIdx.x & 63;
  int token = blockIdx.x*4 + wid;
  const float* xr = x + (size_t)token*DM;
  float4 v = *(const float4*)&xr[lane*4];
  float s  = v.x+v.y+v.z+v.w;
  float ss = v.x*v.x+v.y*v.y+v.z*v.z+v.w*v.w;
  for (int m=1;m<64;m<<=1){ s += __shfl_xor(s,m); ss += __shfl_xor(ss,m); }
  float mu  = s * (1.f/DM);
  float var = ss*(1.f/DM) - mu*mu;
  float rs  = rsqrtf(var + 1e-5f);
  float4 gv = *(const float4*)&g[lane*4];
  float4 bv = *(const float4*)&b[lane*4];
  uint2 o;
  o.x = cvt_pk_bf16((v.x-mu)*rs*gv.x + bv.x, (v.y-mu)*rs*gv.y + bv.y);
  o.y = cvt_pk_bf16((v.z-mu)*rs*gv.z + bv.z, (v.w-mu)*rs*gv.w + bv.w);
  *(uint2*)&xn_bf[(size_t)token*DM + lane*4] = o;
}

// ---------------- MFMA bf16 GEMM ----------------
// ACT: 2=gate-fused final, 5=fused in_proj+qkv, 6=merged W_out|W_o (block half-select)
template<int ACT>
__global__ __launch_bounds__(256) void gemm_mfma(const u16* __restrict__ A,
    const u16* __restrict__ Wt, const float* __restrict__ bias,
    float* __restrict__ C, u16* __restrict__ Cbf, int K, int ldc, int nvalid,
    int qcols, float qscale, const float* __restrict__ xres,
    const float* __restrict__ cat2, u16* __restrict__ vTout,
    u16* __restrict__ qkvout,
    const u16* __restrict__ A2, const u16* __restrict__ Wt2, int K2,
    const float* __restrict__ bias2) {
  __shared__ u16 lds[12288];    // As 128x64 @0 (8192), Bs 64x64 @8192 (4096)
  int tid = threadIdx.x;
  int m0 = blockIdx.y*128;
  int n0 = blockIdx.x*64;
  const u16* Ap = A; const u16* Wp = Wt; int Kp = K; const float* bp = bias;
  int halfsel = 0;
  if (ACT==6){
    halfsel = (blockIdx.x >= 4);
    if (halfsel){ Ap = A2; Wp = Wt2; Kp = K2; bp = bias2; }
    n0 = (blockIdx.x & 3)*64;
  }
  int w = tid>>6, l = tid&63, lq = l&15, lg = l>>4;
  int wm = w>>1, wn = w&1;
  f32x4 acc[4][2] = {};
  for (int k0 = 0; k0 < Kp; k0 += 64) {
#pragma unroll
    for (int i=0;i<4;++i){
      int gid = i*256 + tid;
      int row = gid>>3, g = gid&7;
      *(bf16x8*)&lds[row*64 + ((g ^ (row&7))*8)] =
          *(const bf16x8*)&Ap[(size_t)(m0+row)*Kp + k0 + g*8];
    }
#pragma unroll
    for (int i=0;i<2;++i){
      int gid = i*256 + tid;
      int row = gid>>3, g = gid&7;
      *(bf16x8*)&lds[8192 + row*64 + ((g ^ (row&7))*8)] =
          *(const bf16x8*)&Wp[(size_t)(n0+row)*Kp + k0 + g*8];
    }
    __syncthreads();
#pragma unroll
    for (int ks=0;ks<2;++ks){
      bf16x8 af[4], bfv[2];
#pragma unroll
      for (int mi=0;mi<4;++mi){
        int row = wm*64 + mi*16 + lq;
        af[mi] = *(bf16x8*)&lds[row*64 + (((ks*4+lg) ^ (row&7))*8)];
      }
#pragma unroll
      for (int nj=0;nj<2;++nj){
        int row = wn*32 + nj*16 + lq;
        bfv[nj] = *(bf16x8*)&lds[8192 + row*64 + (((ks*4+lg) ^ (row&7))*8)];
      }
#pragma unroll
      for (int mi=0;mi<4;++mi)
#pragma unroll
        for (int nj=0;nj<2;++nj)
          acc[mi][nj] = __builtin_amdgcn_mfma_f32_16x16x32_bf16(af[mi], bfv[nj], acc[mi][nj], 0,0,0);
    }
    __syncthreads();
  }
#pragma unroll
  for (int mi=0;mi<4;++mi){
#pragma unroll
    for (int nj=0;nj<2;++nj){
#pragma unroll
      for (int r=0;r<4;++r){
        int row = m0 + wm*64 + mi*16 + lg*4 + r;
        int col = n0 + wn*32 + nj*16 + lq;
        if (col < nvalid) {
          float v = acc[mi][nj][r];
          if (col < qcols) v *= qscale;
          if (ACT==2) {
            if (bias) v += bias[col];
            float g = sigmoidf_(v);
            float sv = cat2[(size_t)row*512 + col];
            float av = cat2[(size_t)row*512 + 256 + col];
            C[(size_t)row*256 + col] = xres[(size_t)row*256 + col] + g*sv + (1.f-g)*av;
          } else if (ACT==5) {
            if (col < 1024) {
              Cbf[(size_t)row*1024 + col] = f2bf(v);
            } else {
              int c2 = col - 1024;
              v += bias[c2];
              if (c2 < 256) v *= qscale;
              qkvout[(size_t)row*768 + c2] = f2bf(v);
              if (c2 >= 512) {
                int bb = row>>11, ll = row&2047;
                int hh = (c2-512)>>6, dd = (c2-512)&63;
                vTout[(((size_t)(bb*4+hh))*64 + dd)*SEQ + ll] = f2bf(v);
              }
            }
          } else if (ACT==6) {
            if (bp) v += bp[col];
            C[(size_t)row*512 + halfsel*256 + col] = v;
            Cbf[(size_t)row*512 + halfsel*256 + col] = f2bf(v);
          }
        }
      }
    }
  }
}

// ---------------- co-launched: ssm_pre (conv+xproj+dt, blocks 0..127) | attn (blocks 128..639) ----------------
__global__ __launch_bounds__(256) void attn_ssmpre_kernel(
    const u16* __restrict__ qkvb, const u16* __restrict__ vT,
    u16* __restrict__ Opart, float* __restrict__ ml,
    const u16* __restrict__ xzb, const float* __restrict__ cw,
    const float* __restrict__ cb, u16* __restrict__ xc_bf,
    const u16* __restrict__ Wt_xp, const float* __restrict__ Wdt,
    const float* __restrict__ bdt, float* __restrict__ dblb,
    u16* __restrict__ dtb) {
  __shared__ u16 xcs[32768];      // 64 tok x 512 d, swizzled (64 KB)
  __shared__ float dbls[64][16];  // dt_in slice (4 KB)
  int tid = threadIdx.x;

  if (blockIdx.x < 128) {
    // ================= ssm_pre branch =================
    int bid = blockIdx.x;
    int tok0 = bid*64;
    for (int i=0;i<64;++i){
      int t = i;
      int d2 = tid*2;
      int tg = tok0 + t;
      int lpos = tg & (SEQ-1);
      float acc0 = cb[d2], acc1 = cb[d2+1];
      float4 wA = *(const float4*)&cw[d2*4];
      float4 wB = *(const float4*)&cw[d2*4+4];
      const u16* base = xzb + (size_t)tg*1024 + d2;
      ushort2 v;
      if (lpos>=3){ v = *(const ushort2*)&base[-3*1024]; acc0 += bf2f(v.x)*wA.x; acc1 += bf2f(v.y)*wB.x; }
      if (lpos>=2){ v = *(const ushort2*)&base[-2*1024]; acc0 += bf2f(v.x)*wA.y; acc1 += bf2f(v.y)*wB.y; }
      if (lpos>=1){ v = *(const ushort2*)&base[-1*1024]; acc0 += bf2f(v.x)*wA.z; acc1 += bf2f(v.y)*wB.z; }
      v = *(const ushort2*)&base[0];
      acc0 += bf2f(v.x)*wA.w; acc1 += bf2f(v.y)*wB.w;
      float r0 = acc0 * sigmoidf_(acc0);
      float r1 = acc1 * sigmoidf_(acc1);
      unsigned pk = cvt_pk_bf16(r0, r1);
      *(unsigned*)&xc_bf[(size_t)tg*DI + d2] = pk;
      *(unsigned*)&xcs[t*512 + (((d2>>3) ^ (t&7))*8) + (d2&7)] = pk;
    }
    __syncthreads();
    // ---- xproj MFMA: wave w -> tokens w*16..+15; N=64 (48 valid) ----
    {
      int w = tid>>6, l = tid&63, lq = l&15, lg = l>>4;
      f32x4 acc[4] = {};
      for (int ks=0; ks<16; ++ks){
        int row = w*16 + lq;
        int dcol = ks*32 + lg*8;
        bf16x8 af = *(bf16x8*)&xcs[row*512 + (((dcol>>3) ^ (row&7))*8)];
#pragma unroll
        for (int nt=0; nt<4; ++nt){
          int n = nt*16 + lq;
          bf16x8 bfv = *(const bf16x8*)&Wt_xp[(size_t)n*512 + dcol];
          acc[nt] = __builtin_amdgcn_mfma_f32_16x16x32_bf16(af, bfv, acc[nt], 0,0,0);
        }
      }
#pragma unroll
      for (int nt=0; nt<4; ++nt){
#pragma unroll
        for (int r=0;r<4;++r){
          int t = w*16 + lg*4 + r;
          int n = nt*16 + lq;
          float v = acc[nt][r];
          if (n < 48) dblb[(size_t)(tok0+t)*48 + n] = v;
          if (nt == 0) dbls[t][lq] = v;
        }
      }
    }
    __syncthreads();
    // ---- dt: thread owns cols d2,d2+1; loop tokens ----
    {
      int d2 = tid*2;
      float wdt0[16], wdt1[16];
#pragma unroll
      for (int k=0;k<16;++k){ wdt0[k] = Wdt[k*DI + d2]; wdt1[k] = Wdt[k*DI + d2 + 1]; }
      float b0 = bdt[d2], b1 = bdt[d2+1];
      for (int t=0;t<64;++t){
        float a0 = b0, a1 = b1;
#pragma unroll
        for (int k=0;k<16;++k){ float dk = dbls[t][k]; a0 += dk*wdt0[k]; a1 += dk*wdt1[k]; }
        float sp0 = (a0 > 20.f) ? a0 : log1pf(__expf(a0));
        float sp1 = (a1 > 20.f) ? a1 : log1pf(__expf(a1));
        *(unsigned*)&dtb[(size_t)(tok0+t)*DI + d2] = cvt_pk_bf16(sp0, sp1);
      }
    }
    return;
  }

  // ================= attention branch (barrier-free, direct-L2) =================
  int H = blockIdx.x - 128;        // 0..511
  int cx = H & 7, kk = H >> 3;
  int xq = kk & 7;
  int G  = cx*8 + (kk >> 3);       // 0..63, contiguous per XCD
  int bh = G & 15, s = G >> 4;     // s in 0..3
  int b = bh>>2, h = bh&3;
  int w = tid>>6, l = tid&63;
  int lo32 = l & 31;
  int hi = l >> 5;
  size_t bbase = (size_t)b*SEQ;
  size_t vbase = (size_t)bh*HD*SEQ;
  int q_base = xq*256 + w*64;

  bf16x8 qf[2][4];
#pragma unroll
  for (int qg=0; qg<2; ++qg)
#pragma unroll
    for (int dsl=0; dsl<4; ++dsl)
      qf[qg][dsl] = *(const bf16x8*)&qkvb[(bbase + q_base + qg*32 + lo32)*768 + h*HD + dsl*16 + hi*8];

  float m_[2] = {-1e30f,-1e30f}, l_[2] = {0.f,0.f};
  f32x16 oacc[2][2] = {};

#define EXCH(X, Y, s_own, s_oth) { \
  unsigned xa = (X), yb = (Y); \
  permswap(xa, yb); \
  s_own = (l < 32) ? (X) : xa; \
  s_oth = (l < 32) ? yb : (Y); }

  for (int kt=s*8; kt<s*8+8; ++kt){
#pragma unroll
    for (int t32=0; t32<2; ++t32){
      const u16* kbase = &qkvb[(bbase + (size_t)kt*64 + t32*32 + lo32)*768 + 256 + h*HD + hi*8];
      bf16x8 kf[4];
#pragma unroll
      for (int dsl=0; dsl<4; ++dsl)
        kf[dsl] = *(const bf16x8*)&kbase[dsl*16];
      const u16* vb0 = &vT[vbase + (size_t)(lo32     )*SEQ + kt*64 + t32*32 + hi*8];
      const u16* vb1 = &vT[vbase + (size_t)(32 + lo32)*SEQ + kt*64 + t32*32 + hi*8];
      bf16x8 vf00 = *(const bf16x8*)&vb0[0];
      bf16x8 vf01 = *(const bf16x8*)&vb0[16];
      bf16x8 vf10 = *(const bf16x8*)&vb1[0];
      bf16x8 vf11 = *(const bf16x8*)&vb1[16];

      bf16x8 pf[2][2];
#pragma unroll
      for (int qg=0; qg<2; ++qg){
        f32x16 sacc = {0,0,0,0,0,0,0,0,0,0,0,0,0,0,0,0};
#pragma unroll
        for (int dsl=0; dsl<4; ++dsl)
          sacc = __builtin_amdgcn_mfma_f32_32x32x16_bf16(kf[dsl], qf[qg][dsl], sacc, 0,0,0);

        float tm = sacc[0];
#pragma unroll
        for (int r=1;r<16;++r) tm = fmaxf(tm, sacc[r]);
        tm = fmaxf(tm, xor32f(tm));
        if (__any(tm - m_[qg] > 8.f)) {
          float mn = fmaxf(m_[qg], tm);
          float sc = exp2f(m_[qg] - mn);
          m_[qg] = mn;
          l_[qg] *= sc;
#pragma unroll
          for (int r=0;r<16;++r){ oacc[qg][0][r] *= sc; oacc[qg][1][r] *= sc; }
        }
        float p[16];
        float ps = 0.f;
#pragma unroll
        for (int r=0;r<16;++r){ p[r] = exp2f(sacc[r] - m_[qg]); ps += p[r]; }
        ps += xor32f(ps);
        l_[qg] += ps;

        unsigned A0 = cvt_pk_bf16(p[0],p[1]),  A1 = cvt_pk_bf16(p[2],p[3]);
        unsigned B0 = cvt_pk_bf16(p[4],p[5]),  B1 = cvt_pk_bf16(p[6],p[7]);
        unsigned C0 = cvt_pk_bf16(p[8],p[9]),  C1 = cvt_pk_bf16(p[10],p[11]);
        unsigned D0 = cvt_pk_bf16(p[12],p[13]),D1 = cvt_pk_bf16(p[14],p[15]);
        unsigned s0,s1,s2,s3,s4,s5,s6,s7;
        EXCH(A0,B0,s0,s2); EXCH(A1,B1,s1,s3);
        EXCH(C0,D0,s4,s6); EXCH(C1,D1,s5,s7);
        ((unsigned*)&pf[qg][0])[0]=s0; ((unsigned*)&pf[qg][0])[1]=s1;
        ((unsigned*)&pf[qg][0])[2]=s2; ((unsigned*)&pf[qg][0])[3]=s3;
        ((unsigned*)&pf[qg][1])[0]=s4; ((unsigned*)&pf[qg][1])[1]=s5;
        ((unsigned*)&pf[qg][1])[2]=s6; ((unsigned*)&pf[qg][1])[3]=s7;
      }

      oacc[0][0] = __builtin_amdgcn_mfma_f32_32x32x16_bf16(vf00, pf[0][0], oacc[0][0], 0,0,0);
      oacc[0][0] = __builtin_amdgcn_mfma_f32_32x32x16_bf16(vf01, pf[0][1], oacc[0][0], 0,0,0);
      oacc[0][1] = __builtin_amdgcn_mfma_f32_32x32x16_bf16(vf10, pf[0][0], oacc[0][1], 0,0,0);
      oacc[0][1] = __builtin_amdgcn_mfma_f32_32x32x16_bf16(vf11, pf[0][1], oacc[0][1], 0,0,0);
      oacc[1][0] = __builtin_amdgcn_mfma_f32_32x32x16_bf16(vf00, pf[1][0], oacc[1][0], 0,0,0);
      oacc[1][0] = __builtin_amdgcn_mfma_f32_32x32x16_bf16(vf01, pf[1][1], oacc[1][0], 0,0,0);
      oacc[1][1] = __builtin_amdgcn_mfma_f32_32x32x16_bf16(vf10, pf[1][0], oacc[1][1], 0,0,0);
      oacc[1][1] = __builtin_amdgcn_mfma_f32_32x32x16_bf16(vf11, pf[1][1], oacc[1][1], 0,0,0);
    }
  }
#undef EXCH

  int sidx = bh*NSP + s;
#pragma unroll
  for (int qg=0; qg<2; ++qg){
    size_t rb = ((size_t)sidx*SEQ + q_base + qg*32 + lo32)*64;
#pragma unroll
    for (int dtile=0; dtile<2; ++dtile){
#pragma unroll
      for (int rg=0; rg<4; ++rg){
        uint2 pk;
        pk.x = cvt_pk_bf16(oacc[qg][dtile][rg*4+0], oacc[qg][dtile][rg*4+1]);
        pk.y = cvt_pk_bf16(oacc[qg][dtile][rg*4+2], oacc[qg][dtile][rg*4+3]);
        *(uint2*)&Opart[rb + dtile*32 + rg*8 + 4*hi] = pk;
      }
    }
    if (l < 32){
      ml[((size_t)sidx*SEQ + q_base + qg*32 + lo32)*2    ] = m_[qg];
      ml[((size_t)sidx*SEQ + q_base + qg*32 + lo32)*2 + 1] = l_[qg];
    }
  }
}

// ---------------- chunked selective scan, thread-per-channel (bf16 summaries) ----------------
__global__ __launch_bounds__(512) void scan_p1(const u16* __restrict__ xc_bf,
    const u16* __restrict__ dt, const float* __restrict__ dbl,
    const float* __restrict__ A_log, u16* __restrict__ Pws, u16* __restrict__ Hws) {
  __shared__ float sB[CL][16];
  int d = threadIdx.x;
  int bc = blockIdx.x;          // 0..255
  int b = bc >> 6, c = bc & 63;
  {
    int t = threadIdx.x >> 4, n = threadIdx.x & 15;
    sB[t][n] = dbl[((size_t)b*SEQ + c*CL + t)*48 + DTR + n];
  }
  __syncthreads();
  float An[16];
#pragma unroll
  for (int i=0;i<4;++i){
    float4 a = *(const float4*)&A_log[d*16 + i*4];
    An[i*4+0] = -__expf(a.x); An[i*4+1] = -__expf(a.y);
    An[i*4+2] = -__expf(a.z); An[i*4+3] = -__expf(a.w);
  }
  float h[16] = {};
  float P[16];
#pragma unroll
  for (int n=0;n<16;++n) P[n] = 1.f;
  size_t tok = (size_t)b*SEQ + c*CL;
  for (int t=0;t<CL;++t,++tok){
    float dtv = bf2f(dt[tok*DI+d]);
    float xcv = bf2f(xc_bf[tok*DI+d]);
    float u = dtv*xcv;
    float4 B0 = *(float4*)&sB[t][0];
    float4 B1 = *(float4*)&sB[t][4];
    float4 B2 = *(float4*)&sB[t][8];
    float4 B3 = *(float4*)&sB[t][12];
    float Bv[16] = {B0.x,B0.y,B0.z,B0.w,B1.x,B1.y,B1.z,B1.w,
                    B2.x,B2.y,B2.z,B2.w,B3.x,B3.y,B3.z,B3.w};
#pragma unroll
    for (int n=0;n<16;++n){
      float e = __expf(dtv*An[n]);
      P[n] *= e;
      h[n] = e*h[n] + u*Bv[n];
    }
  }
  size_t base = (((size_t)b*NCH + c)*DI + d)*16;
#pragma unroll
  for (int i=0;i<8;++i){
    *(unsigned*)&Pws[base + i*2] = cvt_pk_bf16(P[i*2], P[i*2+1]);
    *(unsigned*)&Hws[base + i*2] = cvt_pk_bf16(h[i*2], h[i*2+1]);
  }
}

__global__ __launch_bounds__(256) void scan_combine(const u16* __restrict__ Pws,
    const u16* __restrict__ Hws, u16* __restrict__ H0ws) {
  int gid = blockIdx.x*256 + threadIdx.x;  // 0..32767 = (b, d*16+n)
  int b  = gid >> 13;
  int dn = gid & 8191;
  float h0 = 0.f;
#pragma unroll 4
  for (int c=0;c<NCH;++c){
    size_t idx = ((size_t)(b*NCH+c)<<13) + dn;
    H0ws[idx] = f2bf(h0);
    h0 = bf2f(Pws[idx])*h0 + bf2f(Hws[idx]);
  }
}

__global__ __launch_bounds__(512) void scan_p2(const u16* __restrict__ xc_bf,
    const u16* __restrict__ dt, const float* __restrict__ dbl,
    const float* __restrict__ A_log, const float* __restrict__ Dp,
    const u16* __restrict__ xzb, const u16* __restrict__ H0ws,
    u16* __restrict__ ygate_bf) {
  __shared__ float sBC[CL][32];
  int d = threadIdx.x;
  int bc = blockIdx.x;
  int b = bc >> 6, c = bc & 63;
#pragma unroll
  for (int i=0;i<2;++i){
    int idx = i*512 + threadIdx.x;
    int t = idx >> 5, q = idx & 31;
    sBC[t][q] = dbl[((size_t)b*SEQ + c*CL + t)*48 + DTR + q];
  }
  __syncthreads();
  float An[16];
#pragma unroll
  for (int i=0;i<4;++i){
    float4 a = *(const float4*)&A_log[d*16 + i*4];
    An[i*4+0] = -__expf(a.x); An[i*4+1] = -__expf(a.y);
    An[i*4+2] = -__expf(a.z); An[i*4+3] = -__expf(a.w);
  }
  float Dd = Dp[d];
  float h[16];
  size_t base = (((size_t)b*NCH + c)*DI + d)*16;
  {
    bf16x8 h8a = *(const bf16x8*)&H0ws[base];
    bf16x8 h8b = *(const bf16x8*)&H0ws[base+8];
#pragma unroll
    for (int n=0;n<8;++n){ h[n] = bf2f((u16)h8a[n]); h[8+n] = bf2f((u16)h8b[n]); }
  }
  size_t tok = (size_t)b*SEQ + c*CL;
  for (int t=0;t<CL;++t,++tok){
    float dtv = bf2f(dt[tok*DI+d]);
    float xcv = bf2f(xc_bf[tok*DI+d]);
    float zv  = bf2f(xzb[tok*1024 + DI + d]);
    float u = dtv*xcv;
    float4 B0 = *(float4*)&sBC[t][0];
    float4 B1 = *(float4*)&sBC[t][4];
    float4 B2 = *(float4*)&sBC[t][8];
    float4 B3 = *(float4*)&sBC[t][12];
    float4 C0 = *(float4*)&sBC[t][16];
    float4 C1 = *(float4*)&sBC[t][20];
    float4 C2 = *(float4*)&sBC[t][24];
    float4 C3 = *(float4*)&sBC[t][28];
    float Bv[16] = {B0.x,B0.y,B0.z,B0.w,B1.x,B1.y,B1.z,B1.w,
                    B2.x,B2.y,B2.z,B2.w,B3.x,B3.y,B3.z,B3.w};
    float Cv[16] = {C0.x,C0.y,C0.z,C0.w,C1.x,C1.y,C1.z,C1.w,
                    C2.x,C2.y,C2.z,C2.w,C3.x,C3.y,C3.z,C3.w};
    float y = 0.f;
#pragma unroll
    for (int n=0;n<16;++n){
      float e = __expf(dtv*An[n]);
      h[n] = e*h[n] + u*Bv[n];
      y += h[n]*Cv[n];
    }
    y += xcv*Dd;
    ygate_bf[tok*DI + d] = f2bf(y * (zv*sigmoidf_(zv)));
  }
}

// ---------------- merge NSP KV-chunk partials (log2 domain, bf16 partials) -> bf16 attn_o ----------------
__global__ __launch_bounds__(256) void attn_merge_kernel(const u16* __restrict__ Opart,
    const float* __restrict__ ml, u16* __restrict__ attn_bf) {
  int w = threadIdx.x>>6, lane = threadIdx.x&63;
  int R = blockIdx.x*4 + w;        // 0..32767
  int bh = R>>11, q = R&2047;
  float m[NSP], lv[NSP];
#pragma unroll
  for (int s=0;s<NSP;++s){
    m[s]  = ml[((size_t)(bh*NSP+s)*SEQ + q)*2];
    lv[s] = ml[((size_t)(bh*NSP+s)*SEQ + q)*2 + 1];
  }
  float ms = m[0];
#pragma unroll
  for (int s=1;s<NSP;++s) ms = fmaxf(ms, m[s]);
  float o = 0.f, lsum = 0.f;
#pragma unroll
  for (int s=0;s<NSP;++s){
    float wsc = exp2f(m[s]-ms);
    lsum += wsc*lv[s];
    o += wsc*bf2f(Opart[((size_t)(bh*NSP+s)*SEQ + q)*64 + lane]);
  }
  size_t token = (size_t)(bh>>2)*SEQ + q;
  attn_bf[token*DM + (bh&3)*HD + lane] = f2bf(o/lsum);
}

extern "C" void kernel_launch(void* const* d_in, const int* in_sizes, int n_in,
                              void* d_out, int out_size, void* d_ws, size_t ws_size,
                              hipStream_t stream) {
  const float* x      = (const float*)d_in[0];
  const float* ln_g   = (const float*)d_in[1];
  const float* ln_b   = (const float*)d_in[2];
  const float* W_in   = (const float*)d_in[3];
  const float* conv_w = (const float*)d_in[4];
  const float* conv_b = (const float*)d_in[5];
  const float* W_xproj= (const float*)d_in[6];
  const float* W_dt   = (const float*)d_in[7];
  const float* b_dt   = (const float*)d_in[8];
  const float* A_log  = (const float*)d_in[9];
  const float* Dp     = (const float*)d_in[10];
  const float* W_out_m= (const float*)d_in[11];
  const float* W_qkv  = (const float*)d_in[12];
  const float* b_qkv  = (const float*)d_in[13];
  const float* W_o    = (const float*)d_in[14];
  const float* b_o    = (const float*)d_in[15];
  const float* W_gate = (const float*)d_in[16];
  const float* b_gate = (const float*)d_in[17];
  float* out = (float*)d_out;

  float* ws = (float*)d_ws;
  u16*   xn_bf   = (u16*)(ws);                       // 2,097,152 u
  u16*   xzb     = (u16*)(ws + 1048576);             // bf16 xz — live until scan_p2
  u16*   qkv_bf  = (u16*)(ws + 9437184);             // 6,291,456 u
  u16*   xc_bf   = (u16*)(ws + 12582912);            // 4,194,304 u
  float* dblb    = ws + 16777216;                    //   393,216
  u16*   dtb     = (u16*)(ws + 17170432);            // 4,194,304 u (bf16)
  u16*   ygate_bf= (u16*)(ws + 21364736);            // 4,194,304 u
  u16*   attn_bf = (u16*)(ws + 23461888);            // 2,097,152 u
  float* catb    = ws + 24510464;                    // 4,194,304 f (16 MB)
  u16*   catb_bf = (u16*)(ws + 28704768);            // 4,194,304 u
  float* gateb   = ws + 30801920;                    // 2,097,152
  u16*   Wt_all  = (u16*)(ws + 32899072);            //   819,200 u
  // aliases (lifetime-disjoint, SIZE-checked):
  u16*   Opart = (u16*)catb;           // 8,388,608 u16 (16 MB) fits catb exactly.
                                       // written by co-launch -> read by merge -> THEN
                                       // scan_p1 writes Pws (same region, stream-ordered)
  float* mlb   = (float*)xn_bf;        // 262,144 f needed; region holds 1,048,576 f
  u16*   vTb   = (u16*)gateb;          // 4,194,304 u16 = 8 MB = gateb region exactly
  u16*   Pws   = (u16*)catb;           // scan summaries, after merge consumed Opart
  u16*   Hws   = (u16*)(catb + 1048576);
  u16*   H0ws  = (u16*)(catb + 2097152);

  u16* Wt_in   = Wt_all;             // 1024x256  (contiguous with Wt_qkv -> [1792][256])
  u16* Wt_qkv  = Wt_all + 262144;    // 768x256
  u16* Wt_out  = Wt_all + 458752;    // 256x512
  u16* Wt_o    = Wt_all + 589824;    // 256x256
  u16* Wt_gate = Wt_all + 655360;    // 256x512
  u16* Wt_xp   = Wt_all + 786432;    // 64x512 (48 valid + 16 zero rows)

  TcvtArgs ta;
  ta.src[0]=W_in;    ta.dst[0]=Wt_in;   ta.K[0]=256; ta.Nvalid[0]=1024; ta.Npad[0]=1024;
  ta.src[1]=W_qkv;   ta.dst[1]=Wt_qkv;  ta.K[1]=256; ta.Nvalid[1]=768;  ta.Npad[1]=768;
  ta.src[2]=W_out_m; ta.dst[2]=Wt_out;  ta.K[2]=512; ta.Nvalid[2]=256;  ta.Npad[2]=256;
  ta.src[3]=W_o;     ta.dst[3]=Wt_o;    ta.K[3]=256; ta.Nvalid[3]=256;  ta.Npad[3]=256;
  ta.src[4]=W_gate;  ta.dst[4]=Wt_gate; ta.K[4]=512; ta.Nvalid[4]=256;  ta.Npad[4]=256;
  ta.src[5]=W_xproj; ta.dst[5]=Wt_xp;   ta.K[5]=512; ta.Nvalid[5]=48;   ta.Npad[5]=64;
  tcvt_all<<<dim3(8,16,6), 256, 0, stream>>>(ta);

  ln_kernel<<<T_TOK/4, 256, 0, stream>>>(x, ln_g, ln_b, xn_bf);
  gemm_mfma<5><<<dim3(28,64), 256, 0, stream>>>(xn_bf, Wt_in, b_qkv, nullptr, xzb, 256, 0, 1792, 0, QSCALE, nullptr, nullptr, vTb, qkv_bf, nullptr, nullptr, 0, nullptr);
  // co-launch: 128 ssm_pre blocks (conv+xproj+dt) + 512 attn blocks
  attn_ssmpre_kernel<<<640, 256, 0, stream>>>(qkv_bf, vTb, Opart, mlb,
      xzb, conv_w, conv_b, xc_bf, Wt_xp, W_dt, b_dt, dblb, dtb);
  attn_merge_kernel<<<8192, 256, 0, stream>>>(Opart, mlb, attn_bf);
  scan_p1<<<B_SZ*NCH, 512, 0, stream>>>(xc_bf, dtb, dblb, A_log, Pws, Hws);
  scan_combine<<<128, 256, 0, stream>>>(Pws, Hws, H0ws);
  scan_p2<<<B_SZ*NCH, 512, 0, stream>>>(xc_bf, dtb, dblb, A_log, Dp, xzb, H0ws, ygate_bf);
  gemm_mfma<6><<<dim3(8,64), 256, 0, stream>>>(ygate_bf, Wt_out, nullptr, catb, catb_bf, 512, 512, 256, 0, 1.f, nullptr, nullptr, nullptr, nullptr, attn_bf, Wt_o, 256, b_o);
  gemm_mfma<2><<<dim3(4,64), 256, 0, stream>>>(catb_bf, Wt_gate, b_gate, out, nullptr, 512, 256, 256, 0, 1.f, x, catb, nullptr, nullptr, nullptr, nullptr, 0, b_gate);
}

// Round 19
// 232.283 us; speedup vs baseline: 1.2217x; 1.2217x over previous
//
#include <hip/hip_runtime.h>
#include <math.h>

#define B_SZ 4
#define SEQ 2048
#define DM 256
#define DI 512
#define DS 16
#define DTR 16
#define NH 4
#define HD 64
#define T_TOK (B_SZ*SEQ)   // 8192
#define NCH 64             // scan time-chunks
#define CL (SEQ/NCH)       // 32
#define NSP 4              // attn KV splits
#define QSCALE 0.18033688f // 0.125 * log2(e)

typedef short bf16x8 __attribute__((ext_vector_type(8)));
typedef float f32x4  __attribute__((ext_vector_type(4)));
typedef float f32x16 __attribute__((ext_vector_type(16)));
typedef unsigned short u16;

__device__ __forceinline__ float sigmoidf_(float x){ return 1.f/(1.f+__expf(-x)); }
__device__ __forceinline__ u16 f2bf(float x){
  unsigned int u = __float_as_uint(x);
  u += 0x7fffu + ((u>>16)&1u);
  return (u16)(u>>16);
}
__device__ __forceinline__ float bf2f(u16 u){ return __uint_as_float(((unsigned)u)<<16); }
__device__ __forceinline__ unsigned cvt_pk_bf16(float lo, float hi){
  unsigned r;
  asm("v_cvt_pk_bf16_f32 %0, %1, %2" : "=v"(r) : "v"(lo), "v"(hi));
  return r;
}
__device__ __forceinline__ void permswap(unsigned &a, unsigned &b){
  asm volatile("v_permlane32_swap_b32 %0, %1" : "+v"(a), "+v"(b));
}
__device__ __forceinline__ float xor32f(float v){
  unsigned a = __float_as_uint(v), b = a;
  permswap(a, b);
  return __uint_as_float(a);
}

// ---------------- all weight transposes in one kernel: dst[n][k] = bf16(src[k][n]) ----------------
struct TcvtArgs {
  const float* src[6];
  u16* dst[6];
  int K[6];
  int Nvalid[6];
  int Npad[6];
};
__global__ __launch_bounds__(256) void tcvt_all(TcvtArgs a) {
  int wi = blockIdx.z;
  int K = a.K[wi], Nv = a.Nvalid[wi], Np = a.Npad[wi];
  int k0 = blockIdx.x*64, n0 = blockIdx.y*64;
  if (k0 >= K || n0 >= Np) return;
  __shared__ u16 tile[64][65];
  const float* src = a.src[wi];
  u16* dst = a.dst[wi];
  int tn = threadIdx.x & 63, tq = threadIdx.x >> 6;
#pragma unroll
  for (int j=0;j<16;++j){
    int kk = j*4 + tq;
    int n = n0 + tn;
    tile[tn][kk] = (n < Nv) ? f2bf(src[(size_t)(k0+kk)*Nv + n]) : (u16)0;
  }
  __syncthreads();
#pragma unroll
  for (int j=0;j<16;++j){
    int nn = j*4 + tq;
    dst[(size_t)(n0+nn)*K + k0 + tn] = tile[nn][tn];
  }
}

// ---------------- LayerNorm: one wave per token -> bf16 ----------------
__global__ __launch_bounds__(256) void ln_kernel(const float* __restrict__ x,
    const float* __restrict__ g, const float* __restrict__ b,
    u16* __restrict__ xn_bf) {
  int wid = threadIdx.x >> 6;
  int lane = threadIdx.x & 63;
  int token = blockIdx.x*4 + wid;
  const float* xr = x + (size_t)token*DM;
  float4 v = *(const float4*)&xr[lane*4];
  float s  = v.x+v.y+v.z+v.w;
  float ss = v.x*v.x+v.y*v.y+v.z*v.z+v.w*v.w;
  for (int m=1;m<64;m<<=1){ s += __shfl_xor(s,m); ss += __shfl_xor(ss,m); }
  float mu  = s * (1.f/DM);
  float var = ss*(1.f/DM) - mu*mu;
  float rs  = rsqrtf(var + 1e-5f);
  float4 gv = *(const float4*)&g[lane*4];
  float4 bv = *(const float4*)&b[lane*4];
  uint2 o;
  o.x = cvt_pk_bf16((v.x-mu)*rs*gv.x + bv.x, (v.y-mu)*rs*gv.y + bv.y);
  o.y = cvt_pk_bf16((v.z-mu)*rs*gv.z + bv.z, (v.w-mu)*rs*gv.w + bv.w);
  *(uint2*)&xn_bf[(size_t)token*DM + lane*4] = o;
}

// ---------------- MFMA bf16 GEMM ----------------
// ACT: 2=gate-fused final, 5=fused in_proj+qkv, 6=merged W_out|W_o (block half-select)
template<int ACT>
__global__ __launch_bounds__(256) void gemm_mfma(const u16* __restrict__ A,
    const u16* __restrict__ Wt, const float* __restrict__ bias,
    float* __restrict__ C, u16* __restrict__ Cbf, int K, int ldc, int nvalid,
    int qcols, float qscale, const float* __restrict__ xres,
    const float* __restrict__ cat2, u16* __restrict__ vTout,
    u16* __restrict__ qkvout,
    const u16* __restrict__ A2, const u16* __restrict__ Wt2, int K2,
    const float* __restrict__ bias2) {
  __shared__ u16 lds[12288];    // As 128x64 @0 (8192), Bs 64x64 @8192 (4096)
  int tid = threadIdx.x;
  int m0 = blockIdx.y*128;
  int n0 = blockIdx.x*64;
  const u16* Ap = A; const u16* Wp = Wt; int Kp = K; const float* bp = bias;
  int halfsel = 0;
  if (ACT==6){
    halfsel = (blockIdx.x >= 4);
    if (halfsel){ Ap = A2; Wp = Wt2; Kp = K2; bp = bias2; }
    n0 = (blockIdx.x & 3)*64;
  }
  int w = tid>>6, l = tid&63, lq = l&15, lg = l>>4;
  int wm = w>>1, wn = w&1;
  f32x4 acc[4][2] = {};
  for (int k0 = 0; k0 < Kp; k0 += 64) {
#pragma unroll
    for (int i=0;i<4;++i){
      int gid = i*256 + tid;
      int row = gid>>3, g = gid&7;
      *(bf16x8*)&lds[row*64 + ((g ^ (row&7))*8)] =
          *(const bf16x8*)&Ap[(size_t)(m0+row)*Kp + k0 + g*8];
    }
#pragma unroll
    for (int i=0;i<2;++i){
      int gid = i*256 + tid;
      int row = gid>>3, g = gid&7;
      *(bf16x8*)&lds[8192 + row*64 + ((g ^ (row&7))*8)] =
          *(const bf16x8*)&Wp[(size_t)(n0+row)*Kp + k0 + g*8];
    }
    __syncthreads();
#pragma unroll
    for (int ks=0;ks<2;++ks){
      bf16x8 af[4], bfv[2];
#pragma unroll
      for (int mi=0;mi<4;++mi){
        int row = wm*64 + mi*16 + lq;
        af[mi] = *(bf16x8*)&lds[row*64 + (((ks*4+lg) ^ (row&7))*8)];
      }
#pragma unroll
      for (int nj=0;nj<2;++nj){
        int row = wn*32 + nj*16 + lq;
        bfv[nj] = *(bf16x8*)&lds[8192 + row*64 + (((ks*4+lg) ^ (row&7))*8)];
      }
#pragma unroll
      for (int mi=0;mi<4;++mi)
#pragma unroll
        for (int nj=0;nj<2;++nj)
          acc[mi][nj] = __builtin_amdgcn_mfma_f32_16x16x32_bf16(af[mi], bfv[nj], acc[mi][nj], 0,0,0);
    }
    __syncthreads();
  }
#pragma unroll
  for (int mi=0;mi<4;++mi){
#pragma unroll
    for (int nj=0;nj<2;++nj){
#pragma unroll
      for (int r=0;r<4;++r){
        int row = m0 + wm*64 + mi*16 + lg*4 + r;
        int col = n0 + wn*32 + nj*16 + lq;
        if (col < nvalid) {
          float v = acc[mi][nj][r];
          if (col < qcols) v *= qscale;
          if (ACT==2) {
            if (bias) v += bias[col];
            float g = sigmoidf_(v);
            float sv = cat2[(size_t)row*512 + col];
            float av = cat2[(size_t)row*512 + 256 + col];
            C[(size_t)row*256 + col] = xres[(size_t)row*256 + col] + g*sv + (1.f-g)*av;
          } else if (ACT==5) {
            if (col < 1024) {
              Cbf[(size_t)row*1024 + col] = f2bf(v);
            } else {
              int c2 = col - 1024;
              v += bias[c2];
              if (c2 < 256) v *= qscale;
              qkvout[(size_t)row*768 + c2] = f2bf(v);
              if (c2 >= 512) {
                int bb = row>>11, ll = row&2047;
                int hh = (c2-512)>>6, dd = (c2-512)&63;
                vTout[(((size_t)(bb*4+hh))*64 + dd)*SEQ + ll] = f2bf(v);
              }
            }
          } else if (ACT==6) {
            if (bp) v += bp[col];
            C[(size_t)row*512 + halfsel*256 + col] = v;
            Cbf[(size_t)row*512 + halfsel*256 + col] = f2bf(v);
          }
        }
      }
    }
  }
}

// ---------------- depthwise conv (k=4) + SiLU: bf16 in -> bf16 out ----------------
__global__ __launch_bounds__(256) void conv_kernel(const u16* __restrict__ xzb,
    const float* __restrict__ cw, const float* __restrict__ cb,
    u16* __restrict__ xc_bf) {
  int idx = blockIdx.x*256 + threadIdx.x;   // over T_TOK*256
  int d2 = (idx & 255)*2;
  int t = idx >> 8;
  int l = t & (SEQ-1);
  float acc0 = cb[d2], acc1 = cb[d2+1];
  float4 wA = *(const float4*)&cw[d2*4];
  float4 wB = *(const float4*)&cw[d2*4+4];
  const u16* base = xzb + (size_t)t*1024 + d2;
  ushort2 v;
  if (l>=3){ v = *(const ushort2*)&base[-3*1024]; acc0 += bf2f(v.x)*wA.x; acc1 += bf2f(v.y)*wB.x; }
  if (l>=2){ v = *(const ushort2*)&base[-2*1024]; acc0 += bf2f(v.x)*wA.y; acc1 += bf2f(v.y)*wB.y; }
  if (l>=1){ v = *(const ushort2*)&base[-1*1024]; acc0 += bf2f(v.x)*wA.z; acc1 += bf2f(v.y)*wB.z; }
  v = *(const ushort2*)&base[0];
  acc0 += bf2f(v.x)*wA.w; acc1 += bf2f(v.y)*wB.w;
  float r0 = acc0 * sigmoidf_(acc0);
  float r1 = acc1 * sigmoidf_(acc1);
  *(unsigned*)&xc_bf[(size_t)t*DI + d2] = cvt_pk_bf16(r0, r1);
}

// ---------------- xproj GEMM uses gemm template below; dt kernel ----------------
__global__ __launch_bounds__(256) void dt_kernel(const float* __restrict__ dbl,
    const float* __restrict__ Wdt, const float* __restrict__ bdt,
    u16* __restrict__ dt) {
  __shared__ float sdbl[4][16];
  int wid = threadIdx.x>>6, lane = threadIdx.x&63;
  int token = blockIdx.x*4 + wid;
  if (lane < 16) sdbl[wid][lane] = dbl[(size_t)token*48 + lane];
  __syncthreads();
  float din[16];
#pragma unroll
  for (int k=0;k<16;++k) din[k] = sdbl[wid][k];
#pragma unroll
  for (int r=0;r<8;++r){
    int d = lane + r*64;
    float acc = bdt[d];
#pragma unroll
    for (int k=0;k<16;++k) acc += din[k]*Wdt[k*DI+d];
    float sp = (acc > 20.f) ? acc : log1pf(__expf(acc));
    dt[(size_t)token*DI+d] = f2bf(sp);
  }
}

// xproj: C[M,48] = xc_bf @ Wt_xp  (simple ACT-free variant via gemm path)
__global__ __launch_bounds__(256) void xproj_gemm(const u16* __restrict__ A,
    const u16* __restrict__ Wt, float* __restrict__ C) {
  __shared__ u16 lds[12288];
  int tid = threadIdx.x;
  int m0 = blockIdx.y*128, n0 = 0;
  int w = tid>>6, l = tid&63, lq = l&15, lg = l>>4;
  int wm = w>>1, wn = w&1;
  f32x4 acc[4][2] = {};
  for (int k0 = 0; k0 < 512; k0 += 64) {
#pragma unroll
    for (int i=0;i<4;++i){
      int gid = i*256 + tid;
      int row = gid>>3, g = gid&7;
      *(bf16x8*)&lds[row*64 + ((g ^ (row&7))*8)] =
          *(const bf16x8*)&A[(size_t)(m0+row)*512 + k0 + g*8];
    }
#pragma unroll
    for (int i=0;i<2;++i){
      int gid = i*256 + tid;
      int row = gid>>3, g = gid&7;
      *(bf16x8*)&lds[8192 + row*64 + ((g ^ (row&7))*8)] =
          *(const bf16x8*)&Wt[(size_t)(n0+row)*512 + k0 + g*8];
    }
    __syncthreads();
#pragma unroll
    for (int ks=0;ks<2;++ks){
      bf16x8 af[4], bfv[2];
#pragma unroll
      for (int mi=0;mi<4;++mi){
        int row = wm*64 + mi*16 + lq;
        af[mi] = *(bf16x8*)&lds[row*64 + (((ks*4+lg) ^ (row&7))*8)];
      }
#pragma unroll
      for (int nj=0;nj<2;++nj){
        int row = wn*32 + nj*16 + lq;
        bfv[nj] = *(bf16x8*)&lds[8192 + row*64 + (((ks*4+lg) ^ (row&7))*8)];
      }
#pragma unroll
      for (int mi=0;mi<4;++mi)
#pragma unroll
        for (int nj=0;nj<2;++nj)
          acc[mi][nj] = __builtin_amdgcn_mfma_f32_16x16x32_bf16(af[mi], bfv[nj], acc[mi][nj], 0,0,0);
    }
    __syncthreads();
  }
#pragma unroll
  for (int mi=0;mi<4;++mi){
#pragma unroll
    for (int nj=0;nj<2;++nj){
#pragma unroll
      for (int r=0;r<4;++r){
        int row = m0 + wm*64 + mi*16 + lg*4 + r;
        int col = wn*32 + nj*16 + lq;
        if (col < 48) C[(size_t)row*48 + col] = acc[mi][nj][r];
      }
    }
  }
}

// ---------------- chunked selective scan, thread-per-channel (bf16 summaries) ----------------
__global__ __launch_bounds__(512) void scan_p1(const u16* __restrict__ xc_bf,
    const u16* __restrict__ dt, const float* __restrict__ dbl,
    const float* __restrict__ A_log, u16* __restrict__ Pws, u16* __restrict__ Hws) {
  __shared__ float sB[CL][16];
  int d = threadIdx.x;
  int bc = blockIdx.x;          // 0..255
  int b = bc >> 6, c = bc & 63;
  {
    int t = threadIdx.x >> 4, n = threadIdx.x & 15;
    sB[t][n] = dbl[((size_t)b*SEQ + c*CL + t)*48 + DTR + n];
  }
  __syncthreads();
  float An[16];
#pragma unroll
  for (int i=0;i<4;++i){
    float4 a = *(const float4*)&A_log[d*16 + i*4];
    An[i*4+0] = -__expf(a.x); An[i*4+1] = -__expf(a.y);
    An[i*4+2] = -__expf(a.z); An[i*4+3] = -__expf(a.w);
  }
  float h[16] = {};
  float P[16];
#pragma unroll
  for (int n=0;n<16;++n) P[n] = 1.f;
  size_t tok = (size_t)b*SEQ + c*CL;
  for (int t=0;t<CL;++t,++tok){
    float dtv = bf2f(dt[tok*DI+d]);
    float xcv = bf2f(xc_bf[tok*DI+d]);
    float u = dtv*xcv;
    float4 B0 = *(float4*)&sB[t][0];
    float4 B1 = *(float4*)&sB[t][4];
    float4 B2 = *(float4*)&sB[t][8];
    float4 B3 = *(float4*)&sB[t][12];
    float Bv[16] = {B0.x,B0.y,B0.z,B0.w,B1.x,B1.y,B1.z,B1.w,
                    B2.x,B2.y,B2.z,B2.w,B3.x,B3.y,B3.z,B3.w};
#pragma unroll
    for (int n=0;n<16;++n){
      float e = __expf(dtv*An[n]);
      P[n] *= e;
      h[n] = e*h[n] + u*Bv[n];
    }
  }
  size_t base = (((size_t)b*NCH + c)*DI + d)*16;
#pragma unroll
  for (int i=0;i<8;++i){
    *(unsigned*)&Pws[base + i*2] = cvt_pk_bf16(P[i*2], P[i*2+1]);
    *(unsigned*)&Hws[base + i*2] = cvt_pk_bf16(h[i*2], h[i*2+1]);
  }
}

__global__ __launch_bounds__(256) void scan_combine(const u16* __restrict__ Pws,
    const u16* __restrict__ Hws, u16* __restrict__ H0ws) {
  int gid = blockIdx.x*256 + threadIdx.x;  // 0..32767 = (b, d*16+n)
  int b  = gid >> 13;
  int dn = gid & 8191;
  float h0 = 0.f;
#pragma unroll 4
  for (int c=0;c<NCH;++c){
    size_t idx = ((size_t)(b*NCH+c)<<13) + dn;
    H0ws[idx] = f2bf(h0);
    h0 = bf2f(Pws[idx])*h0 + bf2f(Hws[idx]);
  }
}

__global__ __launch_bounds__(512) void scan_p2(const u16* __restrict__ xc_bf,
    const u16* __restrict__ dt, const float* __restrict__ dbl,
    const float* __restrict__ A_log, const float* __restrict__ Dp,
    const u16* __restrict__ xzb, const u16* __restrict__ H0ws,
    u16* __restrict__ ygate_bf) {
  __shared__ float sBC[CL][32];
  int d = threadIdx.x;
  int bc = blockIdx.x;
  int b = bc >> 6, c = bc & 63;
#pragma unroll
  for (int i=0;i<2;++i){
    int idx = i*512 + threadIdx.x;
    int t = idx >> 5, q = idx & 31;
    sBC[t][q] = dbl[((size_t)b*SEQ + c*CL + t)*48 + DTR + q];
  }
  __syncthreads();
  float An[16];
#pragma unroll
  for (int i=0;i<4;++i){
    float4 a = *(const float4*)&A_log[d*16 + i*4];
    An[i*4+0] = -__expf(a.x); An[i*4+1] = -__expf(a.y);
    An[i*4+2] = -__expf(a.z); An[i*4+3] = -__expf(a.w);
  }
  float Dd = Dp[d];
  float h[16];
  size_t base = (((size_t)b*NCH + c)*DI + d)*16;
  {
    bf16x8 h8a = *(const bf16x8*)&H0ws[base];
    bf16x8 h8b = *(const bf16x8*)&H0ws[base+8];
#pragma unroll
    for (int n=0;n<8;++n){ h[n] = bf2f((u16)h8a[n]); h[8+n] = bf2f((u16)h8b[n]); }
  }
  size_t tok = (size_t)b*SEQ + c*CL;
  for (int t=0;t<CL;++t,++tok){
    float dtv = bf2f(dt[tok*DI+d]);
    float xcv = bf2f(xc_bf[tok*DI+d]);
    float zv  = bf2f(xzb[tok*1024 + DI + d]);
    float u = dtv*xcv;
    float4 B0 = *(float4*)&sBC[t][0];
    float4 B1 = *(float4*)&sBC[t][4];
    float4 B2 = *(float4*)&sBC[t][8];
    float4 B3 = *(float4*)&sBC[t][12];
    float4 C0 = *(float4*)&sBC[t][16];
    float4 C1 = *(float4*)&sBC[t][20];
    float4 C2 = *(float4*)&sBC[t][24];
    float4 C3 = *(float4*)&sBC[t][28];
    float Bv[16] = {B0.x,B0.y,B0.z,B0.w,B1.x,B1.y,B1.z,B1.w,
                    B2.x,B2.y,B2.z,B2.w,B3.x,B3.y,B3.z,B3.w};
    float Cv[16] = {C0.x,C0.y,C0.z,C0.w,C1.x,C1.y,C1.z,C1.w,
                    C2.x,C2.y,C2.z,C2.w,C3.x,C3.y,C3.z,C3.w};
    float y = 0.f;
#pragma unroll
    for (int n=0;n<16;++n){
      float e = __expf(dtv*An[n]);
      h[n] = e*h[n] + u*Bv[n];
      y += h[n]*Cv[n];
    }
    y += xcv*Dd;
    ygate_bf[tok*DI + d] = f2bf(y * (zv*sigmoidf_(zv)));
  }
}

// ---------------- MFMA 32x32 flash attention, BARRIER-FREE (operands direct from L2) ----------------
__global__ __launch_bounds__(256) void attn_mfma_kernel(const u16* __restrict__ qkvb,
    const u16* __restrict__ vT,
    u16* __restrict__ Opart, float* __restrict__ ml) {
  int H = blockIdx.x + 8*blockIdx.y + 128*(int)blockIdx.z;   // 0..511
  int cx = H & 7, kk = H >> 3;
  int xq = kk & 7;
  int G  = cx*8 + (kk >> 3);       // 0..63, contiguous per XCD
  int bh = G & 15, s = G >> 4;     // s in 0..3
  int b = bh>>2, h = bh&3;
  int tid = threadIdx.x;
  int w = tid>>6, l = tid&63;
  int lo32 = l & 31;
  int hi = l >> 5;
  size_t bbase = (size_t)b*SEQ;
  size_t vbase = (size_t)bh*HD*SEQ;
  int q_base = xq*256 + w*64;

  bf16x8 qf[2][4];
#pragma unroll
  for (int qg=0; qg<2; ++qg)
#pragma unroll
    for (int dsl=0; dsl<4; ++dsl)
      qf[qg][dsl] = *(const bf16x8*)&qkvb[(bbase + q_base + qg*32 + lo32)*768 + h*HD + dsl*16 + hi*8];

  float m_[2] = {-1e30f,-1e30f}, l_[2] = {0.f,0.f};
  f32x16 oacc[2][2] = {};

#define EXCH(X, Y, s_own, s_oth) { \
  unsigned xa = (X), yb = (Y); \
  permswap(xa, yb); \
  s_own = (l < 32) ? (X) : xa; \
  s_oth = (l < 32) ? yb : (Y); }

  for (int kt=s*8; kt<s*8+8; ++kt){
#pragma unroll
    for (int t32=0; t32<2; ++t32){
      const u16* kbase = &qkvb[(bbase + (size_t)kt*64 + t32*32 + lo32)*768 + 256 + h*HD + hi*8];
      bf16x8 kf[4];
#pragma unroll
      for (int dsl=0; dsl<4; ++dsl)
        kf[dsl] = *(const bf16x8*)&kbase[dsl*16];
      const u16* vb0 = &vT[vbase + (size_t)(lo32     )*SEQ + kt*64 + t32*32 + hi*8];
      const u16* vb1 = &vT[vbase + (size_t)(32 + lo32)*SEQ + kt*64 + t32*32 + hi*8];
      bf16x8 vf00 = *(const bf16x8*)&vb0[0];
      bf16x8 vf01 = *(const bf16x8*)&vb0[16];
      bf16x8 vf10 = *(const bf16x8*)&vb1[0];
      bf16x8 vf11 = *(const bf16x8*)&vb1[16];

      bf16x8 pf[2][2];
#pragma unroll
      for (int qg=0; qg<2; ++qg){
        f32x16 sacc = {0,0,0,0,0,0,0,0,0,0,0,0,0,0,0,0};
#pragma unroll
        for (int dsl=0; dsl<4; ++dsl)
          sacc = __builtin_amdgcn_mfma_f32_32x32x16_bf16(kf[dsl], qf[qg][dsl], sacc, 0,0,0);

        float tm = sacc[0];
#pragma unroll
        for (int r=1;r<16;++r) tm = fmaxf(tm, sacc[r]);
        tm = fmaxf(tm, xor32f(tm));
        if (__any(tm - m_[qg] > 8.f)) {
          float mn = fmaxf(m_[qg], tm);
          float sc = exp2f(m_[qg] - mn);
          m_[qg] = mn;
          l_[qg] *= sc;
#pragma unroll
          for (int r=0;r<16;++r){ oacc[qg][0][r] *= sc; oacc[qg][1][r] *= sc; }
        }
        float p[16];
        float ps = 0.f;
#pragma unroll
        for (int r=0;r<16;++r){ p[r] = exp2f(sacc[r] - m_[qg]); ps += p[r]; }
        ps += xor32f(ps);
        l_[qg] += ps;

        unsigned A0 = cvt_pk_bf16(p[0],p[1]),  A1 = cvt_pk_bf16(p[2],p[3]);
        unsigned B0 = cvt_pk_bf16(p[4],p[5]),  B1 = cvt_pk_bf16(p[6],p[7]);
        unsigned C0 = cvt_pk_bf16(p[8],p[9]),  C1 = cvt_pk_bf16(p[10],p[11]);
        unsigned D0 = cvt_pk_bf16(p[12],p[13]),D1 = cvt_pk_bf16(p[14],p[15]);
        unsigned s0,s1,s2,s3,s4,s5,s6,s7;
        EXCH(A0,B0,s0,s2); EXCH(A1,B1,s1,s3);
        EXCH(C0,D0,s4,s6); EXCH(C1,D1,s5,s7);
        ((unsigned*)&pf[qg][0])[0]=s0; ((unsigned*)&pf[qg][0])[1]=s1;
        ((unsigned*)&pf[qg][0])[2]=s2; ((unsigned*)&pf[qg][0])[3]=s3;
        ((unsigned*)&pf[qg][1])[0]=s4; ((unsigned*)&pf[qg][1])[1]=s5;
        ((unsigned*)&pf[qg][1])[2]=s6; ((unsigned*)&pf[qg][1])[3]=s7;
      }

      oacc[0][0] = __builtin_amdgcn_mfma_f32_32x32x16_bf16(vf00, pf[0][0], oacc[0][0], 0,0,0);
      oacc[0][0] = __builtin_amdgcn_mfma_f32_32x32x16_bf16(vf01, pf[0][1], oacc[0][0], 0,0,0);
      oacc[0][1] = __builtin_amdgcn_mfma_f32_32x32x16_bf16(vf10, pf[0][0], oacc[0][1], 0,0,0);
      oacc[0][1] = __builtin_amdgcn_mfma_f32_32x32x16_bf16(vf11, pf[0][1], oacc[0][1], 0,0,0);
      oacc[1][0] = __builtin_amdgcn_mfma_f32_32x32x16_bf16(vf00, pf[1][0], oacc[1][0], 0,0,0);
      oacc[1][0] = __builtin_amdgcn_mfma_f32_32x32x16_bf16(vf01, pf[1][1], oacc[1][0], 0,0,0);
      oacc[1][1] = __builtin_amdgcn_mfma_f32_32x32x16_bf16(vf10, pf[1][0], oacc[1][1], 0,0,0);
      oacc[1][1] = __builtin_amdgcn_mfma_f32_32x32x16_bf16(vf11, pf[1][1], oacc[1][1], 0,0,0);
    }
  }
#undef EXCH

  int sidx = bh*NSP + s;
#pragma unroll
  for (int qg=0; qg<2; ++qg){
    size_t rb = ((size_t)sidx*SEQ + q_base + qg*32 + lo32)*64;
#pragma unroll
    for (int dtile=0; dtile<2; ++dtile){
#pragma unroll
      for (int rg=0; rg<4; ++rg){
        uint2 pk;
        pk.x = cvt_pk_bf16(oacc[qg][dtile][rg*4+0], oacc[qg][dtile][rg*4+1]);
        pk.y = cvt_pk_bf16(oacc[qg][dtile][rg*4+2], oacc[qg][dtile][rg*4+3]);
        *(uint2*)&Opart[rb + dtile*32 + rg*8 + 4*hi] = pk;
      }
    }
    if (l < 32){
      ml[((size_t)sidx*SEQ + q_base + qg*32 + lo32)*2    ] = m_[qg];
      ml[((size_t)sidx*SEQ + q_base + qg*32 + lo32)*2 + 1] = l_[qg];
    }
  }
}

// ---------------- merge NSP KV-chunk partials (log2 domain, bf16 partials) -> bf16 attn_o ----------------
__global__ __launch_bounds__(256) void attn_merge_kernel(const u16* __restrict__ Opart,
    const float* __restrict__ ml, u16* __restrict__ attn_bf) {
  int w = threadIdx.x>>6, lane = threadIdx.x&63;
  int R = blockIdx.x*4 + w;        // 0..32767
  int bh = R>>11, q = R&2047;
  float m[NSP], lv[NSP];
#pragma unroll
  for (int s=0;s<NSP;++s){
    m[s]  = ml[((size_t)(bh*NSP+s)*SEQ + q)*2];
    lv[s] = ml[((size_t)(bh*NSP+s)*SEQ + q)*2 + 1];
  }
  float ms = m[0];
#pragma unroll
  for (int s=1;s<NSP;++s) ms = fmaxf(ms, m[s]);
  float o = 0.f, lsum = 0.f;
#pragma unroll
  for (int s=0;s<NSP;++s){
    float wsc = exp2f(m[s]-ms);
    lsum += wsc*lv[s];
    o += wsc*bf2f(Opart[((size_t)(bh*NSP+s)*SEQ + q)*64 + lane]);
  }
  size_t token = (size_t)(bh>>2)*SEQ + q;
  attn_bf[token*DM + (bh&3)*HD + lane] = f2bf(o/lsum);
}

extern "C" void kernel_launch(void* const* d_in, const int* in_sizes, int n_in,
                              void* d_out, int out_size, void* d_ws, size_t ws_size,
                              hipStream_t stream) {
  const float* x      = (const float*)d_in[0];
  const float* ln_g   = (const float*)d_in[1];
  const float* ln_b   = (const float*)d_in[2];
  const float* W_in   = (const float*)d_in[3];
  const float* conv_w = (const float*)d_in[4];
  const float* conv_b = (const float*)d_in[5];
  const float* W_xproj= (const float*)d_in[6];
  const float* W_dt   = (const float*)d_in[7];
  const float* b_dt   = (const float*)d_in[8];
  const float* A_log  = (const float*)d_in[9];
  const float* Dp     = (const float*)d_in[10];
  const float* W_out_m= (const float*)d_in[11];
  const float* W_qkv  = (const float*)d_in[12];
  const float* b_qkv  = (const float*)d_in[13];
  const float* W_o    = (const float*)d_in[14];
  const float* b_o    = (const float*)d_in[15];
  const float* W_gate = (const float*)d_in[16];
  const float* b_gate = (const float*)d_in[17];
  float* out = (float*)d_out;

  float* ws = (float*)d_ws;
  u16*   xn_bf   = (u16*)(ws);                       // 2,097,152 u
  u16*   xzb     = (u16*)(ws + 1048576);             // bf16 xz — live until scan_p2
  u16*   qkv_bf  = (u16*)(ws + 9437184);             // 6,291,456 u
  u16*   xc_bf   = (u16*)(ws + 12582912);            // 4,194,304 u
  float* dblb    = ws + 16777216;                    //   393,216
  u16*   dtb     = (u16*)(ws + 17170432);            // 4,194,304 u (bf16)
  u16*   ygate_bf= (u16*)(ws + 21364736);            // 4,194,304 u
  u16*   attn_bf = (u16*)(ws + 23461888);            // 2,097,152 u
  float* catb    = ws + 24510464;                    // 4,194,304 f (16 MB)
  u16*   catb_bf = (u16*)(ws + 28704768);            // 4,194,304 u
  float* gateb   = ws + 30801920;                    // 2,097,152
  u16*   Wt_all  = (u16*)(ws + 32899072);            //   819,200 u
  // aliases (lifetime-disjoint, SIZE-checked):
  u16*   Opart = (u16*)(ws + 1048576); // attn partials: 8.4M u16 in xzb region is WRONG —
                                       // xzb live until scan_p2. Use dedicated: r16 layout:
  Opart = (u16*)(ws + 1048576);        // r16: Opart aliased xzb region AFTER scan_p2 (attn runs after scan_p2)
  float* mlb   = (float*)xn_bf;        // 262,144 f needed; region holds 1,048,576 f
  u16*   vTb   = (u16*)gateb;          // 4,194,304 u16 = 8 MB = gateb region exactly
  u16*   Pws   = (u16*)catb;           // bf16 scan summaries before catb written (gemm6)
  u16*   Hws   = (u16*)(catb + 1048576);
  u16*   H0ws  = (u16*)(catb + 2097152);

  u16* Wt_in   = Wt_all;             // 1024x256  (contiguous with Wt_qkv -> [1792][256])
  u16* Wt_qkv  = Wt_all + 262144;    // 768x256
  u16* Wt_out  = Wt_all + 458752;    // 256x512
  u16* Wt_o    = Wt_all + 589824;    // 256x256
  u16* Wt_gate = Wt_all + 655360;    // 256x512
  u16* Wt_xp   = Wt_all + 786432;    // 64x512 (48 valid + 16 zero rows)

  TcvtArgs ta;
  ta.src[0]=W_in;    ta.dst[0]=Wt_in;   ta.K[0]=256; ta.Nvalid[0]=1024; ta.Npad[0]=1024;
  ta.src[1]=W_qkv;   ta.dst[1]=Wt_qkv;  ta.K[1]=256; ta.Nvalid[1]=768;  ta.Npad[1]=768;
  ta.src[2]=W_out_m; ta.dst[2]=Wt_out;  ta.K[2]=512; ta.Nvalid[2]=256;  ta.Npad[2]=256;
  ta.src[3]=W_o;     ta.dst[3]=Wt_o;    ta.K[3]=256; ta.Nvalid[3]=256;  ta.Npad[3]=256;
  ta.src[4]=W_gate;  ta.dst[4]=Wt_gate; ta.K[4]=512; ta.Nvalid[4]=256;  ta.Npad[4]=256;
  ta.src[5]=W_xproj; ta.dst[5]=Wt_xp;   ta.K[5]=512; ta.Nvalid[5]=48;   ta.Npad[5]=64;
  tcvt_all<<<dim3(8,16,6), 256, 0, stream>>>(ta);

  ln_kernel<<<T_TOK/4, 256, 0, stream>>>(x, ln_g, ln_b, xn_bf);
  gemm_mfma<5><<<dim3(28,64), 256, 0, stream>>>(xn_bf, Wt_in, b_qkv, nullptr, xzb, 256, 0, 1792, 0, QSCALE, nullptr, nullptr, vTb, qkv_bf, nullptr, nullptr, 0, nullptr);
  conv_kernel<<<T_TOK, 256, 0, stream>>>(xzb, conv_w, conv_b, xc_bf);
  xproj_gemm<<<dim3(1,64), 256, 0, stream>>>(xc_bf, Wt_xp, dblb);
  dt_kernel<<<T_TOK/4, 256, 0, stream>>>(dblb, W_dt, b_dt, dtb);
  scan_p1<<<B_SZ*NCH, 512, 0, stream>>>(xc_bf, dtb, dblb, A_log, Pws, Hws);
  scan_combine<<<128, 256, 0, stream>>>(Pws, Hws, H0ws);
  scan_p2<<<B_SZ*NCH, 512, 0, stream>>>(xc_bf, dtb, dblb, A_log, Dp, xzb, H0ws, ygate_bf);
  attn_mfma_kernel<<<dim3(8, 16, 4), 256, 0, stream>>>(qkv_bf, vTb, Opart, mlb);
  attn_merge_kernel<<<8192, 256, 0, stream>>>(Opart, mlb, attn_bf);
  gemm_mfma<6><<<dim3(8,64), 256, 0, stream>>>(ygate_bf, Wt_out, nullptr, catb, catb_bf, 512, 512, 256, 0, 1.f, nullptr, nullptr, nullptr, nullptr, attn_bf, Wt_o, 256, b_o);
  gemm_mfma<2><<<dim3(4,64), 256, 0, stream>>>(catb_bf, Wt_gate, b_gate, out, nullptr, 512, 256, 256, 0, 1.f, x, catb, nullptr, nullptr, nullptr, nullptr, 0, b_gate);
}